// Round 12
// baseline (19.750 us; speedup 1.0000x reference)
//
#include <hip/hip_runtime.h>

#define NATOMS 8192
#define NFREE  4096

constexpr int TPB = 256;            // threads per block (4 waves)
constexpr int IPT = 8;              // i-atoms per thread (4 packed f32x2 groups)
constexpr int TI  = TPB * IPT;      // 2048 i-atoms per block
constexpr int JT  = 16;             // j-atoms held in registers per block
constexpr int GI  = NATOMS / TI;    // 4 i-slabs
constexpr int GJ  = NATOMS / JT;    // 512 j-tiles
constexpr int TPS = TI / JT;        // 128 j-tiles spanning one i-slab
// Triangle grid: slab x dispatches j-tiles y in [TPS*x, GJ) -> 512-128x blocks.
__device__ __constant__ const int S_START[GI + 1] = {0, 512, 896, 1152, 1280};
constexpr int NVBLK = 1280;         // 5 blocks/CU

typedef __attribute__((ext_vector_type(2))) float f32x2;

// d = a * broadcast(b.lo) + c   (VOP3P op_sel: both result halves read src1's low reg)
__device__ __forceinline__ f32x2 pk_fma_blo(f32x2 a, f32x2 b, f32x2 c) {
    f32x2 d;
    asm("v_pk_fma_f32 %0, %1, %2, %3 op_sel:[0,0,0] op_sel_hi:[1,0,1]"
        : "=v"(d) : "v"(a), "v"(b), "v"(c));
    return d;
}
// d = a * broadcast(b.hi) + c
__device__ __forceinline__ f32x2 pk_fma_bhi(f32x2 a, f32x2 b, f32x2 c) {
    f32x2 d;
    asm("v_pk_fma_f32 %0, %1, %2, %3 op_sel:[0,1,0] op_sel_hi:[1,1,1]"
        : "=v"(d) : "v"(a), "v"(b), "v"(c));
    return d;
}
// d = a + broadcast(b.hi)
__device__ __forceinline__ f32x2 pk_add_bhi(f32x2 a, f32x2 b) {
    f32x2 d;
    asm("v_pk_add_f32 %0, %1, %2 op_sel:[0,1] op_sel_hi:[1,1]"
        : "=v"(d) : "v"(a), "v"(b));
    return d;
}

__device__ __forceinline__ float wave_reduce(float v) {
#pragma unroll
    for (int off = 32; off > 0; off >>= 1)
        v += __shfl_down(v, off, 64);
    return v;
}

// Triangle all-pairs sum of 1/r over i<j, coords direct from q/x0
// (free_idx = arange(NFREE): atoms [0,NFREE) from q, rest from x0; slab/tile
// boundaries never straddle NFREE). r2 = si + sj - 2 xi.xj, (-2xi) prescaled.
// The j-tile lives in REGISTERS (block-uniform values): the inner loop has
// zero memory operations -- no LDS pipe contention, no load latency.
__global__ __launch_bounds__(TPB) void pair_kernel(const float* __restrict__ q,
                                                   const float* __restrict__ x0,
                                                   float* __restrict__ vpart) {
    const int bid = blockIdx.x;

    int x = 0;
#pragma unroll
    for (int e = 1; e < GI; ++e) x += (bid >= S_START[e]);
    const int y  = bid - S_START[x] + TPS * x;
    const int i0 = x * TI;
    const int j0 = y * JT;
    const int t  = threadIdx.x;

    // i-side: prescaled (-2x) and |x|^2, packed as 2 atoms per f32x2.
    const float* isrc = (i0 < NFREE) ? q : x0;
    f32x2 ax2[IPT / 2], ay2[IPT / 2], az2[IPT / 2], s2[IPT / 2];
    float acc[IPT];
    int m[IPT];
    const int rel0 = j0 - i0;
#pragma unroll
    for (int k = 0; k < IPT; ++k) {
        const int ia = i0 + t + k * TPB;
        float xx = isrc[3 * ia + 0], yy = isrc[3 * ia + 1], zz = isrc[3 * ia + 2];
        ax2[k / 2][k & 1] = -2.f * xx;
        ay2[k / 2][k & 1] = -2.f * yy;
        az2[k / 2][k & 1] = -2.f * zz;
        s2[k / 2][k & 1]  = fmaf(xx, xx, fmaf(yy, yy, zz * zz));
        acc[k] = 0.f;
        m[k] = t + k * TPB - rel0;   // keep iff m[k] < j_local (diag band only)
    }

    // j-tile: uniform loads (compiler scalarizes), packed once into register
    // pairs (x,y) and (z,|x|^2). Loop-invariant -> all movs land in prologue.
    const float* jp = ((j0 < NFREE) ? q : x0) + 3 * j0;
    f32x2 pxy[JT], pzw[JT];
#pragma unroll
    for (int jj = 0; jj < JT; ++jj) {
        float jx = jp[3 * jj + 0], jy = jp[3 * jj + 1], jz = jp[3 * jj + 2];
        float jw = fmaf(jx, jx, fmaf(jy, jy, jz * jz));
        pxy[jj][0] = jx; pxy[jj][1] = jy;
        pzw[jj][0] = jz; pzw[jj][1] = jw;
    }

    if (rel0 < TI) {
        // Diagonal-band tile: keep only i<j (select also drops the i==j inf/NaN).
#pragma unroll
        for (int j = 0; j < JT; ++j) {
#pragma unroll
            for (int g = 0; g < IPT / 2; ++g) {
                f32x2 d = pk_fma_blo(ax2[g], pxy[j], s2[g]);
                d = pk_fma_bhi(ay2[g], pxy[j], d);
                d = pk_fma_blo(az2[g], pzw[j], d);
                d = pk_add_bhi(d, pzw[j]);
                float r0 = __builtin_amdgcn_rsqf(d.x);
                float r1 = __builtin_amdgcn_rsqf(d.y);
                acc[2 * g + 0] += (m[2 * g + 0] < j) ? r0 : 0.f;
                acc[2 * g + 1] += (m[2 * g + 1] < j) ? r1 : 0.f;
            }
        }
    } else {
#pragma unroll
        for (int j = 0; j < JT; ++j) {
#pragma unroll
            for (int g = 0; g < IPT / 2; ++g) {
                f32x2 d = pk_fma_blo(ax2[g], pxy[j], s2[g]);
                d = pk_fma_bhi(ay2[g], pxy[j], d);
                d = pk_fma_blo(az2[g], pzw[j], d);
                d = pk_add_bhi(d, pzw[j]);
                acc[2 * g + 0] += __builtin_amdgcn_rsqf(d.x);
                acc[2 * g + 1] += __builtin_amdgcn_rsqf(d.y);
            }
        }
    }

    float v = ((acc[0] + acc[1]) + (acc[2] + acc[3])) +
              ((acc[4] + acc[5]) + (acc[6] + acc[7]));
    v = wave_reduce(v);
    __shared__ float s[TPB / 64];
    int lane = t & 63, wid = t >> 6;
    if (lane == 0) s[wid] = v;
    __syncthreads();
    if (t == 0)
        vpart[bid] = (s[0] + s[1]) + (s[2] + s[3]);
}

// out = 0.5*sum(qd^2) - 2*sum(vpart); single block, deterministic order.
__global__ void finalize(const float* __restrict__ vpart,
                         const float4* __restrict__ qd4,   // qd as 3072 float4
                         float* __restrict__ out) {
    float v = 0.f;
    for (int i = threadIdx.x; i < NVBLK; i += TPB) v += vpart[i];
    float tq = 0.f;
    for (int i = threadIdx.x; i < (NFREE * 3) / 4; i += TPB) {
        float4 u = qd4[i];
        tq += fmaf(u.x, u.x, fmaf(u.y, u.y, fmaf(u.z, u.z, u.w * u.w)));
    }
    v = wave_reduce(v);
    tq = wave_reduce(tq);
    __shared__ float sv[TPB / 64], st[TPB / 64];
    int lane = threadIdx.x & 63, wid = threadIdx.x >> 6;
    if (lane == 0) { sv[wid] = v; st[wid] = tq; }
    __syncthreads();
    if (threadIdx.x == 0) {
        float V = (sv[0] + sv[1]) + (sv[2] + sv[3]);
        float T = (st[0] + st[1]) + (st[2] + st[3]);
        out[0] = 0.5f * T - 2.0f * V;   // V2 = 2 * sum_{i<j} 1/r
    }
}

extern "C" void kernel_launch(void* const* d_in, const int* in_sizes, int n_in,
                              void* d_out, int out_size, void* d_ws, size_t ws_size,
                              hipStream_t stream) {
    const float* q  = (const float*)d_in[0];
    const float* qd = (const float*)d_in[1];
    const float* x0 = (const float*)d_in[2];
    float* out = (float*)d_out;

    float* vpart = (float*)d_ws;

    pair_kernel<<<NVBLK, TPB, 0, stream>>>(q, x0, vpart);
    finalize<<<1, TPB, 0, stream>>>(vpart, (const float4*)qd, out);
}

// Round 13
// 17.600 us; speedup vs baseline: 1.1221x; 1.1221x over previous
//
#include <hip/hip_runtime.h>

#define NATOMS 8192
#define NFREE  4096

constexpr int TPB = 512;            // threads per block (8 waves) -- TLP x2 vs R9
constexpr int IPT = 2;              // i-atoms per thread (1 packed f32x2 group)
constexpr int TI  = TPB * IPT;      // 1024 i-atoms per block (same tile as R9)
constexpr int JT  = 32;             // j-atoms staged in LDS per block
constexpr int GI  = NATOMS / TI;    // 8 i-slabs
constexpr int GJ  = NATOMS / JT;    // 256 j-tiles
constexpr int TPS = TI / JT;        // 32 j-tiles spanning one i-slab
// Triangle grid: slab x dispatches j-tiles y in [TPS*x, GJ).
__device__ __constant__ const int S_START[GI + 1] = {0, 256, 480, 672, 832, 960, 1056, 1120, 1152};
constexpr int NVBLK = 1152;         // 4.5 blocks/CU x 8 waves -> ~32 waves/CU resident

typedef __attribute__((ext_vector_type(2))) float f32x2;

// d = a * broadcast(b.lo) + c   (VOP3P op_sel: both result halves read src1's low reg)
__device__ __forceinline__ f32x2 pk_fma_blo(f32x2 a, f32x2 b, f32x2 c) {
    f32x2 d;
    asm("v_pk_fma_f32 %0, %1, %2, %3 op_sel:[0,0,0] op_sel_hi:[1,0,1]"
        : "=v"(d) : "v"(a), "v"(b), "v"(c));
    return d;
}
// d = a * broadcast(b.hi) + c
__device__ __forceinline__ f32x2 pk_fma_bhi(f32x2 a, f32x2 b, f32x2 c) {
    f32x2 d;
    asm("v_pk_fma_f32 %0, %1, %2, %3 op_sel:[0,1,0] op_sel_hi:[1,1,1]"
        : "=v"(d) : "v"(a), "v"(b), "v"(c));
    return d;
}
// d = a + broadcast(b.hi)
__device__ __forceinline__ f32x2 pk_add_bhi(f32x2 a, f32x2 b) {
    f32x2 d;
    asm("v_pk_add_f32 %0, %1, %2 op_sel:[0,1] op_sel_hi:[1,1]"
        : "=v"(d) : "v"(a), "v"(b));
    return d;
}

__device__ __forceinline__ float wave_reduce(float v) {
#pragma unroll
    for (int off = 32; off > 0; off >>= 1)
        v += __shfl_down(v, off, 64);
    return v;
}

// Triangle all-pairs sum of 1/r over i<j, coords direct from q/x0
// (free_idx = arange(NFREE): atoms [0,NFREE) from q, rest from x0; slab/tile
// boundaries never straddle NFREE). r2 = si + sj - 2 xi.xj, (-2xi) prescaled.
// Same tile geometry as the 17.3us version; only TPB 256->512 (TLP x2).
__global__ __launch_bounds__(TPB) void pair_kernel(const float* __restrict__ q,
                                                   const float* __restrict__ x0,
                                                   float* __restrict__ vpart) {
    __shared__ float4 sj[JT];
    const int bid = blockIdx.x;

    int x = 0;
#pragma unroll
    for (int e = 1; e < GI; ++e) x += (bid >= S_START[e]);
    const int y  = bid - S_START[x] + TPS * x;
    const int i0 = x * TI;
    const int j0 = y * JT;
    const int t  = threadIdx.x;

    // Stage j-tile into LDS as (x, y, z, |x|^2).
    if (t < JT) {
        const int ja = j0 + t;
        const float* p = (ja < NFREE) ? (q + 3 * ja) : (x0 + 3 * ja);
        float xx = p[0], yy = p[1], zz = p[2];
        sj[t] = make_float4(xx, yy, zz, fmaf(xx, xx, fmaf(yy, yy, zz * zz)));
    }

    // i-side: prescaled (-2x) and |x|^2, 2 atoms packed in one f32x2 group.
    const float* isrc = (i0 < NFREE) ? q : x0;
    f32x2 ax2, ay2, az2, s2;
    float acc[IPT];
    int m[IPT];
    const int rel0 = j0 - i0;
#pragma unroll
    for (int k = 0; k < IPT; ++k) {
        const int ia = i0 + t + k * TPB;
        float xx = isrc[3 * ia + 0], yy = isrc[3 * ia + 1], zz = isrc[3 * ia + 2];
        ax2[k] = -2.f * xx;
        ay2[k] = -2.f * yy;
        az2[k] = -2.f * zz;
        s2[k]  = fmaf(xx, xx, fmaf(yy, yy, zz * zz));
        acc[k] = 0.f;
        m[k] = t + k * TPB - rel0;   // keep iff m[k] < j_local (diag band only)
    }
    __syncthreads();

    if (rel0 < TI) {
        // Diagonal-band tile: keep only i<j (select also drops the i==j inf/NaN).
#pragma unroll 8
        for (int j = 0; j < JT; ++j) {
            const float4 pj = sj[j];
            f32x2 pxy; pxy.x = pj.x; pxy.y = pj.y;
            f32x2 pzw; pzw.x = pj.z; pzw.y = pj.w;
            f32x2 d = pk_fma_blo(ax2, pxy, s2);
            d = pk_fma_bhi(ay2, pxy, d);
            d = pk_fma_blo(az2, pzw, d);
            d = pk_add_bhi(d, pzw);
            float r0 = __builtin_amdgcn_rsqf(d.x);
            float r1 = __builtin_amdgcn_rsqf(d.y);
            acc[0] += (m[0] < j) ? r0 : 0.f;
            acc[1] += (m[1] < j) ? r1 : 0.f;
        }
    } else {
#pragma unroll 8
        for (int j = 0; j < JT; ++j) {
            const float4 pj = sj[j];
            f32x2 pxy; pxy.x = pj.x; pxy.y = pj.y;
            f32x2 pzw; pzw.x = pj.z; pzw.y = pj.w;
            f32x2 d = pk_fma_blo(ax2, pxy, s2);
            d = pk_fma_bhi(ay2, pxy, d);
            d = pk_fma_blo(az2, pzw, d);
            d = pk_add_bhi(d, pzw);
            acc[0] += __builtin_amdgcn_rsqf(d.x);
            acc[1] += __builtin_amdgcn_rsqf(d.y);
        }
    }

    float v = acc[0] + acc[1];
    v = wave_reduce(v);
    __shared__ float s[TPB / 64];
    int lane = t & 63, wid = t >> 6;
    if (lane == 0) s[wid] = v;
    __syncthreads();
    if (t == 0) {
        float vt = 0.f;
#pragma unroll
        for (int w = 0; w < TPB / 64; ++w) vt += s[w];
        vpart[bid] = vt;
    }
}

// out = 0.5*sum(qd^2) - 2*sum(vpart); single block, deterministic order.
__global__ void finalize(const float* __restrict__ vpart,
                         const float4* __restrict__ qd4,   // qd as 3072 float4
                         float* __restrict__ out) {
    float v = 0.f;
    for (int i = threadIdx.x; i < NVBLK; i += 256) v += vpart[i];
    float tq = 0.f;
    for (int i = threadIdx.x; i < (NFREE * 3) / 4; i += 256) {
        float4 u = qd4[i];
        tq += fmaf(u.x, u.x, fmaf(u.y, u.y, fmaf(u.z, u.z, u.w * u.w)));
    }
    v = wave_reduce(v);
    tq = wave_reduce(tq);
    __shared__ float sv[4], st[4];
    int lane = threadIdx.x & 63, wid = threadIdx.x >> 6;
    if (lane == 0) { sv[wid] = v; st[wid] = tq; }
    __syncthreads();
    if (threadIdx.x == 0) {
        float V = (sv[0] + sv[1]) + (sv[2] + sv[3]);
        float T = (st[0] + st[1]) + (st[2] + st[3]);
        out[0] = 0.5f * T - 2.0f * V;   // V2 = 2 * sum_{i<j} 1/r
    }
}

extern "C" void kernel_launch(void* const* d_in, const int* in_sizes, int n_in,
                              void* d_out, int out_size, void* d_ws, size_t ws_size,
                              hipStream_t stream) {
    const float* q  = (const float*)d_in[0];
    const float* qd = (const float*)d_in[1];
    const float* x0 = (const float*)d_in[2];
    float* out = (float*)d_out;

    float* vpart = (float*)d_ws;

    pair_kernel<<<NVBLK, TPB, 0, stream>>>(q, x0, vpart);
    finalize<<<1, 256, 0, stream>>>(vpart, (const float4*)qd, out);
}